// Round 10
// baseline (200.527 us; speedup 1.0000x reference)
//
#include <hip/hip_runtime.h>
#include <math.h>

typedef __attribute__((ext_vector_type(8))) short bf16x8;
typedef __attribute__((ext_vector_type(4))) float f32x4;
typedef unsigned short ushort_t;

static __device__ inline unsigned short f2bf(float f) {
    union { float f; unsigned u; } v; v.f = f;
    unsigned r = v.u + 0x7fff + ((v.u >> 16) & 1);
    return (unsigned short)(r >> 16);
}

#if defined(__has_builtin)
#  if __has_builtin(__builtin_amdgcn_cvt_pk_bf16_f32)
#    define HAVE_PK_BF16 1
#  endif
#endif

static __device__ inline unsigned pk2bf(float a, float b) {
#ifdef HAVE_PK_BF16
    auto r = __builtin_amdgcn_cvt_pk_bf16_f32(a, b);
    unsigned u; __builtin_memcpy(&u, &r, 4);
    return u;
#else
    return (unsigned)f2bf(a) | ((unsigned)f2bf(b) << 16);
#endif
}

// ---------------------------------------------------------------------------
// Fused pre-pass.
//  blocks < 3072 : fp32->bf16 convert of row/col emb + Wq/Wk/Wv/Wout.
//  blocks >= 3072: mask row -> 64-byte bitmask with the all-masked rule
//  FOLDED IN (all-masked row => all bits 0 => keep everything). The 33.5 MB
//  mask is read exactly once in the whole pipeline.
// ---------------------------------------------------------------------------
__global__ __launch_bounds__(256) void convert_allm(const float* __restrict__ a0,
                                                    const float* __restrict__ a1,
                                                    const float* __restrict__ a2,
                                                    const float* __restrict__ a3,
                                                    const float* __restrict__ a4,
                                                    const float* __restrict__ a5,
                                                    const int* __restrict__ mask,
                                                    ushort_t* __restrict__ dst,
                                                    unsigned char* __restrict__ bmask) {
    if (blockIdx.x < 3072) {
        const size_t e = ((size_t)blockIdx.x * 256 + threadIdx.x) * 4;
        const float* src; size_t off;
        if      (e < 1048576) { src = a0; off = 0; }
        else if (e < 2097152) { src = a1; off = 1048576; }
        else if (e < 2359296) { src = a2; off = 2097152; }
        else if (e < 2621440) { src = a3; off = 2359296; }
        else if (e < 2883584) { src = a4; off = 2621440; }
        else                  { src = a5; off = 2883584; }
        const float4 v = *(const float4*)(src + (e - off));
        uint2 o; o.x = pk2bf(v.x, v.y); o.y = pk2bf(v.z, v.w);
        *(uint2*)(dst + e) = o;
    } else {
        const int bid  = blockIdx.x - 3072;         // 0..4095
        const int w    = threadIdx.x >> 6;
        const int lane = threadIdx.x & 63;
        const int row  = bid * 4 + w;               // bh*512 + r
        const int* mp = mask + (size_t)row * 512 + lane * 8;
        const int4 m0 = *(const int4*)mp;
        const int4 m1 = *(const int4*)(mp + 4);
        unsigned bits = 0;
        bits |= (m0.x != 0) ? 1u   : 0u;
        bits |= (m0.y != 0) ? 2u   : 0u;
        bits |= (m0.z != 0) ? 4u   : 0u;
        bits |= (m0.w != 0) ? 8u   : 0u;
        bits |= (m1.x != 0) ? 16u  : 0u;
        bits |= (m1.y != 0) ? 32u  : 0u;
        bits |= (m1.z != 0) ? 64u  : 0u;
        bits |= (m1.w != 0) ? 128u : 0u;
        const bool all_masked = (__all(bits == 255u) != 0);
        bmask[(size_t)row * 64 + lane] = all_masked ? 0 : (unsigned char)bits;
    }
}

// ---------------------------------------------------------------------------
// Q/K/V projections. 64x64 tile, grid (32,8,3), register prefetch + DUAL
// k-chain (k<256 / k>=256) for 2x in-flight loads in the latency-bound regime.
// z=0: Q; z=1: K; z=2: V stored transposed Vt[bh][d][c].
// ---------------------------------------------------------------------------
__global__ __launch_bounds__(256) void gemm_qkv(const ushort_t* __restrict__ rowb,
                                                const ushort_t* __restrict__ colb,
                                                const ushort_t* __restrict__ Wqb,
                                                const ushort_t* __restrict__ Wkb,
                                                const ushort_t* __restrict__ Wvb,
                                                ushort_t* __restrict__ Qb,
                                                ushort_t* __restrict__ Kb,
                                                ushort_t* __restrict__ Vt) {
    const int z = blockIdx.z;
    const ushort_t* A = (z == 0) ? rowb : colb;
    const ushort_t* B = (z == 0) ? Wqb : (z == 1) ? Wkb : Wvb;

    const int t    = threadIdx.x;
    const int w    = t >> 6;
    const int lane = t & 63;
    const int quad = lane >> 4;
    const int sl   = lane & 15;
    const int m0 = blockIdx.x * 64 + (w >> 1) * 32;
    const int n0 = blockIdx.y * 64 + (w & 1) * 32;

    const ushort_t* ap0 = A + (size_t)(m0 + sl) * 512 + quad * 8;
    const ushort_t* ap1 = A + (size_t)(m0 + 16 + sl) * 512 + quad * 8;
    const ushort_t* bp0 = B + (size_t)(n0 + sl) * 512 + quad * 8;
    const ushort_t* bp1 = B + (size_t)(n0 + 16 + sl) * 512 + quad * 8;

    f32x4 accA[2][2] = {}, accB[2][2] = {};

    bf16x8 a0A = *(const bf16x8*)ap0,         a1A = *(const bf16x8*)ap1;
    bf16x8 b0A = *(const bf16x8*)bp0,         b1A = *(const bf16x8*)bp1;
    bf16x8 a0B = *(const bf16x8*)(ap0 + 256), a1B = *(const bf16x8*)(ap1 + 256);
    bf16x8 b0B = *(const bf16x8*)(bp0 + 256), b1B = *(const bf16x8*)(bp1 + 256);

    for (int ks = 0; ks < 8; ++ks) {
        bf16x8 na0A, na1A, nb0A, nb1A, na0B, na1B, nb0B, nb1B;
        if (ks < 7) {
            const int o = (ks + 1) * 32;
            na0A = *(const bf16x8*)(ap0 + o);       na1A = *(const bf16x8*)(ap1 + o);
            nb0A = *(const bf16x8*)(bp0 + o);       nb1A = *(const bf16x8*)(bp1 + o);
            na0B = *(const bf16x8*)(ap0 + 256 + o); na1B = *(const bf16x8*)(ap1 + 256 + o);
            nb0B = *(const bf16x8*)(bp0 + 256 + o); nb1B = *(const bf16x8*)(bp1 + 256 + o);
        }
        accA[0][0] = __builtin_amdgcn_mfma_f32_16x16x32_bf16(a0A, b0A, accA[0][0], 0, 0, 0);
        accA[0][1] = __builtin_amdgcn_mfma_f32_16x16x32_bf16(a0A, b1A, accA[0][1], 0, 0, 0);
        accA[1][0] = __builtin_amdgcn_mfma_f32_16x16x32_bf16(a1A, b0A, accA[1][0], 0, 0, 0);
        accA[1][1] = __builtin_amdgcn_mfma_f32_16x16x32_bf16(a1A, b1A, accA[1][1], 0, 0, 0);
        accB[0][0] = __builtin_amdgcn_mfma_f32_16x16x32_bf16(a0B, b0B, accB[0][0], 0, 0, 0);
        accB[0][1] = __builtin_amdgcn_mfma_f32_16x16x32_bf16(a0B, b1B, accB[0][1], 0, 0, 0);
        accB[1][0] = __builtin_amdgcn_mfma_f32_16x16x32_bf16(a1B, b0B, accB[1][0], 0, 0, 0);
        accB[1][1] = __builtin_amdgcn_mfma_f32_16x16x32_bf16(a1B, b1B, accB[1][1], 0, 0, 0);
        a0A = na0A; a1A = na1A; b0A = nb0A; b1A = nb1A;
        a0B = na0B; a1B = na1B; b0B = nb0B; b1B = nb1B;
    }

#pragma unroll
    for (int rs = 0; rs < 2; ++rs)
#pragma unroll
        for (int cs = 0; cs < 2; ++cs) {
            const f32x4 acc = accA[rs][cs] + accB[rs][cs];
            const int n = n0 + cs * 16 + sl;
            if (z == 2) {
                const int mb   = m0 + rs * 16 + quad * 4;
                const int bidx = mb >> 9, c = mb & 511;
                const int h = n >> 6, d = n & 63;
                ushort4 o;
                o.x = f2bf(acc[0]); o.y = f2bf(acc[1]);
                o.z = f2bf(acc[2]); o.w = f2bf(acc[3]);
                *(ushort4*)(Vt + (size_t)(((bidx * 8 + h) * 64 + d)) * 512 + c) = o;
            } else {
                ushort_t* C = (z == 0) ? Qb : Kb;
#pragma unroll
                for (int reg = 0; reg < 4; ++reg) {
                    const int m = m0 + rs * 16 + quad * 4 + reg;
                    C[(size_t)m * 512 + n] = f2bf(acc[reg]);
                }
            }
        }
}

// ---------------------------------------------------------------------------
// Final GEMM: out = Aoutb(bf16) @ Woutb(bf16)^T, fp32 out.
// 32x32 tile (wave = 16x16), grid (64,16) = 1024 blocks (4 blocks/CU — the
// old 256-block shape ran at 1 wave/SIMD), dual k-chain.
// ---------------------------------------------------------------------------
__global__ __launch_bounds__(256) void gemm_out(const ushort_t* __restrict__ A,
                                                const ushort_t* __restrict__ B,
                                                float* __restrict__ C) {
    const int t    = threadIdx.x;
    const int w    = t >> 6;
    const int lane = t & 63;
    const int quad = lane >> 4;
    const int sl   = lane & 15;
    const int m0 = blockIdx.x * 32 + (w >> 1) * 16;
    const int n0 = blockIdx.y * 32 + (w & 1) * 16;

    const ushort_t* ap = A + (size_t)(m0 + sl) * 512 + quad * 8;
    const ushort_t* bp = B + (size_t)(n0 + sl) * 512 + quad * 8;

    f32x4 accA = {0.f, 0.f, 0.f, 0.f}, accB = {0.f, 0.f, 0.f, 0.f};

    bf16x8 aA = *(const bf16x8*)ap,         bA = *(const bf16x8*)bp;
    bf16x8 aB = *(const bf16x8*)(ap + 256), bB = *(const bf16x8*)(bp + 256);

    for (int ks = 0; ks < 8; ++ks) {
        bf16x8 naA, nbA, naB, nbB;
        if (ks < 7) {
            const int o = (ks + 1) * 32;
            naA = *(const bf16x8*)(ap + o);       nbA = *(const bf16x8*)(bp + o);
            naB = *(const bf16x8*)(ap + 256 + o); nbB = *(const bf16x8*)(bp + 256 + o);
        }
        accA = __builtin_amdgcn_mfma_f32_16x16x32_bf16(aA, bA, accA, 0, 0, 0);
        accB = __builtin_amdgcn_mfma_f32_16x16x32_bf16(aB, bB, accB, 0, 0, 0);
        aA = naA; bA = nbA; aB = naB; bB = nbB;
    }

    const f32x4 acc = accA + accB;
    const int n = n0 + sl;
#pragma unroll
    for (int reg = 0; reg < 4; ++reg) {
        const int m = m0 + quad * 4 + reg;
        C[(size_t)m * 512 + n] = acc[reg];
    }
}

// ---------------------------------------------------------------------------
// dot + MLP + bitmask + exp, v8 (= v7 with the 33.5 MB mask read replaced by
// a 1 MB folded bitmask: one b32 word per m-tile epilogue).
// 512 threads, grid (16,16,4).
// ---------------------------------------------------------------------------
__global__ __launch_bounds__(512) void dot_mlp_v8(const ushort_t* __restrict__ Qb,
                                                  const ushort_t* __restrict__ Kb,
                                                  const float* __restrict__ cost,
                                                  const float* __restrict__ W1,
                                                  const float* __restrict__ W2,
                                                  const unsigned* __restrict__ bmask,
                                                  ushort_t* __restrict__ tbuf,
                                                  float* __restrict__ lpart) {
    __shared__ ushort_t Xs[1024 * 18];      // 36 KB
    __shared__ ushort_t hidS[8 * 16 * 36];  // 9 KB
    __shared__ ushort_t W1fs[128 * 16];     // 4 KB
    __shared__ ushort_t W2ss[8 * 128];      // 2 KB

    const int b  = blockIdx.z;
    const int r0 = blockIdx.y * 32;
    const int c0 = blockIdx.x * 32;
    const int t    = threadIdx.x;
    const int w    = t >> 6;
    const int lane = t & 63;
    const int quad = lane >> 4;
    const int sl   = lane & 15;

    const bf16x8 zf = {0, 0, 0, 0, 0, 0, 0, 0};

    if (t < 128) {
        float s = 0.f;
#pragma unroll
        for (int h = 0; h < 8; ++h) {
            W1fs[t * 16 + h] = f2bf(W1[t * 16 + 2 * h]);
            s += W1[t * 16 + 2 * h + 1];
        }
        W1fs[t * 16 + 8] = f2bf(s);
#pragma unroll
        for (int k = 9; k < 16; ++k) W1fs[t * 16 + k] = 0;
    }
#pragma unroll
    for (int i = 0; i < 2; ++i) W2ss[t + i * 512] = f2bf(W2[t + i * 512]);

#pragma unroll
    for (int i = 0; i < 2; ++i) {
        const int cell = t + i * 512;
        const int rl = cell >> 5, cl = cell & 31;
        unsigned* base = (unsigned*)(Xs + cell * 18 + 8);
        base[0] = (unsigned)f2bf(cost[((size_t)b * 512 + r0 + rl) * 512 + c0 + cl]);
        base[1] = 0; base[2] = 0; base[3] = 0; base[4] = 0;
    }

    // --- Phase A: heads h0=2*(w&3), h0+1 for r-half rs=w>>2; packed writes ---
    {
        const int hp = w & 3;
        const int h0 = hp * 2;
        const int rs = w >> 2;
        bf16x8 af[2][2], bfr[2][2][2];
#pragma unroll
        for (int hh = 0; hh < 2; ++hh)
#pragma unroll
            for (int ks = 0; ks < 2; ++ks) {
                af[hh][ks] = *(const bf16x8*)(Qb +
                    ((size_t)(b * 512 + r0 + rs * 16 + sl) * 512 + (h0 + hh) * 64 + ks * 32 + quad * 8));
#pragma unroll
                for (int cs = 0; cs < 2; ++cs)
                    bfr[hh][cs][ks] = *(const bf16x8*)(Kb +
                        ((size_t)(b * 512 + c0 + cs * 16 + sl) * 512 + (h0 + hh) * 64 + ks * 32 + quad * 8));
            }
        f32x4 dacc[2][2];
#pragma unroll
        for (int hh = 0; hh < 2; ++hh)
#pragma unroll
            for (int cs = 0; cs < 2; ++cs) {
                f32x4 acc = {0.f, 0.f, 0.f, 0.f};
                acc = __builtin_amdgcn_mfma_f32_16x16x32_bf16(af[hh][0], bfr[hh][cs][0], acc, 0, 0, 0);
                acc = __builtin_amdgcn_mfma_f32_16x16x32_bf16(af[hh][1], bfr[hh][cs][1], acc, 0, 0, 0);
                dacc[hh][cs] = acc;
            }
#pragma unroll
        for (int cs = 0; cs < 2; ++cs)
#pragma unroll
            for (int reg = 0; reg < 4; ++reg) {
                const int cell = (rs * 16 + quad * 4 + reg) * 32 + cs * 16 + sl;
                ((unsigned*)Xs)[cell * 9 + hp] =
                    pk2bf(dacc[0][cs][reg] * 0.125f, dacc[1][cs][reg] * 0.125f);
            }
    }

    __syncthreads();

    // --- Phase B ---
    bf16x8 bw1[8];
#pragma unroll
    for (int nt = 0; nt < 8; ++nt)
        bw1[nt] = (quad < 2) ? *(const bf16x8*)&W1fs[(nt * 16 + sl) * 16 + quad * 8] : zf;
    bf16x8 bw2[4];
#pragma unroll
    for (int ks = 0; ks < 4; ++ks) {
        union { ushort_t s[8]; bf16x8 v; } tu;
#pragma unroll
        for (int i = 0; i < 8; ++i) {
            const int p  = quad * 8 + i;
            const int jc = (p >> 1) | ((p & 1) << 4);
            tu.s[i] = (sl < 8) ? W2ss[sl * 128 + ks * 32 + jc] : (ushort_t)0;
        }
        bw2[ks] = tu.v;
    }

    ushort_t* hidW = hidS + w * (16 * 36);

    float rsum[4] = {0.f, 0.f, 0.f, 0.f};

#pragma unroll
    for (int mt = 0; mt < 8; ++mt) {
        const int gmt = w * 8 + mt;
        const int cb  = gmt * 16;

        bf16x8 a1 = zf;
        if (quad < 2) {
            const unsigned* xr = (const unsigned*)Xs + (size_t)(cb + sl) * 9 + quad * 4;
            union { unsigned u[4]; bf16x8 v; } tmp;
            tmp.u[0] = xr[0]; tmp.u[1] = xr[1]; tmp.u[2] = xr[2]; tmp.u[3] = xr[3];
            a1 = tmp.v;
        }

        f32x4 acc2 = {0.f, 0.f, 0.f, 0.f};
#pragma unroll
        for (int ks = 0; ks < 4; ++ks) {
            f32x4 z = {0.f, 0.f, 0.f, 0.f};
            const f32x4 h0 = __builtin_amdgcn_mfma_f32_16x16x32_bf16(a1, bw1[2 * ks],     z, 0, 0, 0);
            const f32x4 h1 = __builtin_amdgcn_mfma_f32_16x16x32_bf16(a1, bw1[2 * ks + 1], z, 0, 0, 0);
#pragma unroll
            for (int rp = 0; rp < 4; ++rp)
                ((unsigned*)hidW)[(quad * 4 + rp) * 18 + sl] =
                    pk2bf(fmaxf(h0[rp], 0.f), fmaxf(h1[rp], 0.f));
            union { uint2 u2[2]; bf16x8 v; } tu;
            const ushort_t* hp2 = hidW + sl * 36 + quad * 8;
            tu.u2[0] = *(const uint2*)hp2;
            tu.u2[1] = *(const uint2*)(hp2 + 4);
            acc2 = __builtin_amdgcn_mfma_f32_16x16x32_bf16(tu.v, bw2[ks], acc2, 0, 0, 0);
        }

        // epilogue: bitmask -> exp -> bf16 t store + partial row sum
        float psum = 0.f;
        if (sl < 8) {
            const int r = r0 + (gmt >> 1);
            const int cbase = c0 + (gmt & 1) * 16 + quad * 4;
            const size_t rowoff = (size_t)(b * 8 + sl) * 512 + r;
            const unsigned mw = bmask[rowoff * 16 + (c0 >> 5)];
            const unsigned bits = (mw >> ((gmt & 1) * 16 + quad * 4)) & 0xFu;
            float tv0 = (bits & 1u) ? 0.f : __expf(acc2[0]);
            float tv1 = (bits & 2u) ? 0.f : __expf(acc2[1]);
            float tv2 = (bits & 4u) ? 0.f : __expf(acc2[2]);
            float tv3 = (bits & 8u) ? 0.f : __expf(acc2[3]);
            ushort4 o;
            o.x = f2bf(tv0); o.y = f2bf(tv1); o.z = f2bf(tv2); o.w = f2bf(tv3);
            *(ushort4*)&tbuf[rowoff * 512 + cbase] = o;
            psum = tv0 + tv1 + tv2 + tv3;
        }
        psum += __shfl_xor(psum, 16, 64);
        psum += __shfl_xor(psum, 32, 64);
        rsum[mt >> 1] += psum;
    }

    if (quad == 0 && sl < 8) {
#pragma unroll
        for (int i = 0; i < 4; ++i) {
            const size_t rowoff = (size_t)(b * 8 + sl) * 512 + (r0 + w * 4 + i);
            lpart[rowoff * 16 + blockIdx.x] = rsum[i];
        }
    }
}

// ---------------------------------------------------------------------------
// PV + normalize: O[b][r][h*64+d] = (t @ Vt^T) / sum(t).
// grid (32 r-tiles of 16, 32 bh), 256 threads.
// ---------------------------------------------------------------------------
__global__ __launch_bounds__(256) void pv_norm(const ushort_t* __restrict__ tbuf,
                                               const float* __restrict__ lpart,
                                               const ushort_t* __restrict__ Vt,
                                               ushort_t* __restrict__ Aout) {
    __shared__ float lsum[16];

    const int t    = threadIdx.x;
    const int w    = t >> 6;
    const int lane = t & 63;
    const int quad = lane >> 4;
    const int sl   = lane & 15;
    const int rt = blockIdx.x;
    const int bh = blockIdx.y;
    const int r0 = rt * 16;

    if (t < 16) {
        const float* lp = lpart + ((size_t)bh * 512 + r0 + t) * 16;
        const float4 s0 = *(const float4*)lp;
        const float4 s1 = *(const float4*)(lp + 4);
        const float4 s2 = *(const float4*)(lp + 8);
        const float4 s3 = *(const float4*)(lp + 12);
        lsum[t] = (s0.x + s0.y + s0.z + s0.w) + (s1.x + s1.y + s1.z + s1.w) +
                  (s2.x + s2.y + s2.z + s2.w) + (s3.x + s3.y + s3.z + s3.w);
    }
    __syncthreads();

    const ushort_t* tb = tbuf + (size_t)bh * 512 * 512;
    const ushort_t* vb = Vt + (size_t)bh * 64 * 512;
    const int n0w = w * 16;

    f32x4 acc = {0.f, 0.f, 0.f, 0.f};
    for (int ks = 0; ks < 16; ++ks) {
        const bf16x8 ta = *(const bf16x8*)(tb + (size_t)(r0 + sl) * 512 + ks * 32 + quad * 8);
        const bf16x8 bv = *(const bf16x8*)(vb + (size_t)(n0w + sl) * 512 + ks * 32 + quad * 8);
        acc = __builtin_amdgcn_mfma_f32_16x16x32_bf16(ta, bv, acc, 0, 0, 0);
    }

    const int bidx = bh >> 3, h = bh & 7;
    ushort_t* Cb = Aout + (size_t)bidx * 512 * 512 + h * 64;
    const int n = n0w + sl;
#pragma unroll
    for (int reg = 0; reg < 4; ++reg) {
        const int m = r0 + quad * 4 + reg;
        const float inv = 1.f / lsum[quad * 4 + reg];
        Cb[(size_t)m * 512 + n] = f2bf(acc[reg] * inv);
    }
}

// ---------------------------------------------------------------------------
extern "C" void kernel_launch(void* const* d_in, const int* in_sizes, int n_in,
                              void* d_out, int out_size, void* d_ws, size_t ws_size,
                              hipStream_t stream) {
    const float* row_emb = (const float*)d_in[0];
    const float* col_emb = (const float*)d_in[1];
    const float* cost    = (const float*)d_in[2];
    const int*   mask    = (const int*)d_in[3];
    const float* Wq      = (const float*)d_in[4];
    const float* Wk      = (const float*)d_in[5];
    const float* Wv      = (const float*)d_in[6];
    const float* Wmix1   = (const float*)d_in[7];
    const float* Wmix2   = (const float*)d_in[8];
    const float* Wout    = (const float*)d_in[9];
    float* out = (float*)d_out;

    char* ws = (char*)d_ws;
    const size_t MB = (size_t)1 << 20;
    ushort_t* convDst = (ushort_t*)ws;                       // 6 MB bf16 region
    ushort_t* rowb  = (ushort_t*)(ws);
    ushort_t* colb  = (ushort_t*)(ws + 2 * MB);
    ushort_t* Wqb   = (ushort_t*)(ws + 4 * MB);
    ushort_t* Wkb   = (ushort_t*)(ws + 4 * MB + 512 * 1024);
    ushort_t* Wvb   = (ushort_t*)(ws + 5 * MB);
    ushort_t* Woutb = (ushort_t*)(ws + 5 * MB + 512 * 1024);
    ushort_t* Qb    = (ushort_t*)(ws + 6 * MB);              // bf16 [b*512+r][512]
    ushort_t* Kb    = (ushort_t*)(ws + 8 * MB);
    ushort_t* Vt    = (ushort_t*)(ws + 10 * MB);             // bf16 [bh][d][c]
    ushort_t* Aoutb = (ushort_t*)(ws + 12 * MB);             // bf16 [b*512+r][512]
    ushort_t* tbuf  = (ushort_t*)(ws + 16 * MB);             // bf16 [bh][r][c] 16.8 MB
    float* lpart    = (float*)(ws + 34 * MB);                // fp32 [bh*512+r][16] 1 MB
    unsigned char* bmaskBuf = (unsigned char*)(ws + 35 * MB);// 1 MB folded bitmask

    convert_allm<<<7168, 256, 0, stream>>>(row_emb, col_emb, Wq, Wk, Wv, Wout,
                                           mask, convDst, bmaskBuf);

    gemm_qkv<<<dim3(32, 8, 3), 256, 0, stream>>>(rowb, colb, Wqb, Wkb, Wvb, Qb, Kb, Vt);

    dot_mlp_v8<<<dim3(16, 16, 4), 512, 0, stream>>>(Qb, Kb, cost, Wmix1, Wmix2,
                                                    (const unsigned*)bmaskBuf, tbuf, lpart);

    pv_norm<<<dim3(32, 32), 256, 0, stream>>>(tbuf, lpart, Vt, Aoutb);

    gemm_out<<<dim3(64, 16), 256, 0, stream>>>(Aoutb, Woutb, out);
}